// Round 2
// baseline (499.952 us; speedup 1.0000x reference)
//
#include <hip/hip_runtime.h>

// MeanSpikeClassifier: interval-graph connected components.
// N = 96*96 = 9216 pixels, T = 64 steps, out = masks[N,N] ++ mean_grid[N] (f32).
//
// adj(i,j) = (1 - |v_i - v_j| >= 0.6) is an interval graph on the value line.
// Components = maximal value-runs not split by a "gap" (a value with no
// adjacent value above it). component_id(i) = #gap-start values < v_i.
// labels[i] = min pixel index in component (== reference while_loop fixpoint).
//
// masks is ultra-sparse: exactly N ones (pixel n lights row labels[n]).
//
// R1/R2 change: hipMemsetAsync on the 340 MB region showed 4x HBM write
// amplification (WRITE_SIZE 1,327,248 KB for a 331,776 KB buffer -> effective
// 1.55 TB/s). Replaced by k_write: a fused zero+mask writer using coalesced
// nontemporal dwordx4 stores (1024 B/wave-instr, full 64B lines only).
// Non-root rows (all but ~1) are a pure streaming-zero path.
// R2: __builtin_nontemporal_store requires a clang vector type, not HIP's
// float4 class -> use ext_vector_type(4) float.

#define N_PIX 9216

typedef float  f32x4 __attribute__((ext_vector_type(4)));
typedef int    i32x4 __attribute__((ext_vector_type(4)));

// K1: per-pixel mean of late steps; also init compmin/is_root/ngaps (ws is
// re-poisoned to 0xAA before every timed launch, so init must happen per call).
__global__ void k_means(const float* __restrict__ spike, const int* __restrict__ cs_p,
                        int T, float* __restrict__ v, float* __restrict__ out_grid,
                        int* __restrict__ compmin, int* __restrict__ is_root,
                        int* __restrict__ ngaps) {
    int n = blockIdx.x * blockDim.x + threadIdx.x;
    if (n >= N_PIX) return;
    int cs = cs_p[0];
    int start = cs - 1;
    if (start < 0) start = 0;
    if (start > T - 1) start = T - 1;
    float s = 0.0f;
    for (int t = start; t < T; ++t)       // coalesced across n for each t
        s += spike[(size_t)t * N_PIX + n];
    float val = s / (float)(T - start);
    v[n] = val;
    out_grid[n] = val;
    compmin[n] = 0x7fffffff;
    is_root[n] = 0;
    if (n == 0) *ngaps = 0;
}

// K2: one block per pixel k — is k a "gap start"?
// gap(k) := (exists v_j > v_k) && (no j with v_j > v_k && 1-(v_j-v_k) >= 0.6f)
// Exact float predicate of the reference (monotone in the diff).
__global__ void __launch_bounds__(256) k_gaps(const float* __restrict__ v,
                                              float* __restrict__ gaps,
                                              int* __restrict__ ngaps) {
    int k = blockIdx.x;
    float vk = v[k];
    int hasG = 0, hasAdj = 0;
    for (int j = threadIdx.x; j < N_PIX; j += 256) {
        float vj = v[j];                   // 36 KB array, L1/L2-resident
        if (vj > vk) {
            hasG = 1;
            if (1.0f - (vj - vk) >= 0.6f) hasAdj = 1;
        }
    }
    __shared__ int sG, sA;
    if (threadIdx.x == 0) { sG = 0; sA = 0; }
    __syncthreads();
    if (hasG)   atomicOr(&sG, 1);
    if (hasAdj) atomicOr(&sA, 1);
    __syncthreads();
    if (threadIdx.x == 0 && sG && !sA) {
        int idx = atomicAdd(ngaps, 1);     // order-independent downstream
        gaps[idx] = vk;
    }
}

// K3: component id = #gap values strictly below v_i; per-component min index.
__global__ void k_ids(const float* __restrict__ v, const float* __restrict__ gaps,
                      const int* __restrict__ ngaps, int* __restrict__ gid,
                      int* __restrict__ compmin) {
    int i = blockIdx.x * blockDim.x + threadIdx.x;
    if (i >= N_PIX) return;
    float vi = v[i];
    int ng = *ngaps;                       // ~0-2 for this data
    int g = 0;
    for (int t = 0; t < ng; ++t) g += (gaps[t] < vi) ? 1 : 0;
    gid[i] = g;
    atomicMin(&compmin[g], i);
}

// K3b: resolve per-pixel label; mark root rows. (Races on is_root write the
// same value 1 -> benign.)
__global__ void k_labels(const int* __restrict__ gid, const int* __restrict__ compmin,
                         int* __restrict__ labels, int* __restrict__ is_root) {
    int n = blockIdx.x * blockDim.x + threadIdx.x;
    if (n >= N_PIX) return;
    int lab = compmin[gid[n]];
    labels[n] = lab;
    is_root[lab] = 1;
}

// K4: fused zero + mask write. One block per output row r.
// Row = 9216 floats = 2304 float4 = 9 iters of 256 threads; base offset
// r*36864 B is 64B-aligned, stores are fully coalesced dwordx4 (nontemporal:
// pure streaming data, no reuse — don't churn L2).
__global__ void __launch_bounds__(256) k_write(const int* __restrict__ labels,
                                               const int* __restrict__ is_root,
                                               float* __restrict__ out) {
    int r = blockIdx.x;
    f32x4* orow = reinterpret_cast<f32x4*>(out + (size_t)r * N_PIX);
    if (is_root[r] == 0) {                 // common path: all but ~1 row
        const f32x4 z = {0.f, 0.f, 0.f, 0.f};
        #pragma unroll
        for (int it = 0; it < (N_PIX / 4) / 256; ++it) {
            int i = it * 256 + threadIdx.x;
            __builtin_nontemporal_store(z, &orow[i]);
        }
    } else {                               // root row: compare labels (36 KB, L1)
        const i32x4* lab4 = reinterpret_cast<const i32x4*>(labels);
        #pragma unroll
        for (int it = 0; it < (N_PIX / 4) / 256; ++it) {
            int i = it * 256 + threadIdx.x;
            i32x4 l = lab4[i];
            f32x4 m;
            m.x = (l.x == r) ? 1.0f : 0.0f;
            m.y = (l.y == r) ? 1.0f : 0.0f;
            m.z = (l.z == r) ? 1.0f : 0.0f;
            m.w = (l.w == r) ? 1.0f : 0.0f;
            __builtin_nontemporal_store(m, &orow[i]);
        }
    }
}

extern "C" void kernel_launch(void* const* d_in, const int* in_sizes, int n_in,
                              void* d_out, int out_size, void* d_ws, size_t ws_size,
                              hipStream_t stream) {
    const float* spike = (const float*)d_in[0];
    const int* cs = (const int*)d_in[1];
    int T = in_sizes[0] / N_PIX;           // 64

    float* out = (float*)d_out;
    float* out_grid = out + (size_t)N_PIX * N_PIX;

    // workspace layout (~220 KB)
    float* v       = (float*)d_ws;
    float* gaps    = v + N_PIX;
    int*   ngaps   = (int*)(gaps + N_PIX);
    int*   gid     = ngaps + 4;
    int*   compmin = gid + N_PIX;
    int*   labels  = compmin + N_PIX;
    int*   is_root = labels + N_PIX;

    k_means  <<<(N_PIX + 255) / 256, 256, 0, stream>>>(spike, cs, T, v, out_grid,
                                                       compmin, is_root, ngaps);
    k_gaps   <<<N_PIX, 256, 0, stream>>>(v, gaps, ngaps);
    k_ids    <<<(N_PIX + 255) / 256, 256, 0, stream>>>(v, gaps, ngaps, gid, compmin);
    k_labels <<<(N_PIX + 255) / 256, 256, 0, stream>>>(gid, compmin, labels, is_root);
    k_write  <<<N_PIX, 256, 0, stream>>>(labels, is_root, out);
}